// Round 2
// baseline (817.138 us; speedup 1.0000x reference)
//
#include <hip/hip_runtime.h>
#include <math.h>

#define BB 256
#define SS 257
#define CVD 1024
#define CTD 768
#define NTOK 256          // S-1
#define MROWS (BB*4)      // 1024
#define EPS_LN 1e-5f
#define NEG_SLOPE 0.01f

// ---------------- Phase A: cosine similarity, one wave per token-row ----------
__global__ __launch_bounds__(256) void cos_kernel(const float* __restrict__ vis,
                                                  const float* __restrict__ inf,
                                                  float* __restrict__ cosv) {
    int wave = threadIdx.x >> 6;
    int lane = threadIdx.x & 63;
    int r = blockIdx.x * 4 + wave;              // 0 .. 65535
    int b = r >> 8, s = r & 255;
    const float4* vrow = (const float4*)(vis + (size_t)b * SS * CVD + (size_t)(s + 1) * CVD);
    const float4* irow = (const float4*)(inf + (size_t)b * SS * CVD + (size_t)(s + 1) * CVD);
    float vv = 0.f, ii = 0.f, vi = 0.f;
#pragma unroll
    for (int j = 0; j < 4; ++j) {
        float4 v = vrow[j * 64 + lane];
        float4 w = irow[j * 64 + lane];
        vv += v.x * v.x + v.y * v.y + v.z * v.z + v.w * v.w;
        ii += w.x * w.x + w.y * w.y + w.z * w.z + w.w * w.w;
        vi += v.x * w.x + v.y * w.y + v.z * w.z + v.w * w.w;
    }
#pragma unroll
    for (int off = 32; off; off >>= 1) {
        vv += __shfl_xor(vv, off);
        ii += __shfl_xor(ii, off);
        vi += __shfl_xor(vi, off);
    }
    if (lane == 0) cosv[r] = vi / sqrtf(vv * ii);
}

// ---------------- Phase B1: top-3 per batch (ties -> lower index, like lax.top_k)
__global__ __launch_bounds__(64) void topk_kernel(const float* __restrict__ cosv,
                                                  int* __restrict__ idx) {
    int b = blockIdx.x;
    int lane = threadIdx.x;
    float v[4];
    int id[4];
#pragma unroll
    for (int j = 0; j < 4; ++j) {
        id[j] = lane + j * 64;
        v[j] = cosv[b * NTOK + id[j]];
    }
    for (int round = 0; round < 3; ++round) {
        float bv = v[0];
        int bi = id[0];
#pragma unroll
        for (int j = 1; j < 4; ++j)
            if (v[j] > bv) { bv = v[j]; bi = id[j]; }   // strict > keeps lowest idx in-lane
#pragma unroll
        for (int off = 32; off; off >>= 1) {
            float ov = __shfl_xor(bv, off);
            int oi = __shfl_xor(bi, off);
            if (ov > bv || (ov == bv && oi < bi)) { bv = ov; bi = oi; }
        }
        if (lane == 0) idx[b * 3 + round] = bi;
#pragma unroll
        for (int j = 0; j < 4; ++j)
            if (id[j] == bi) v[j] = -3.402823466e38f;
    }
}

// ---------------- Phase B2: gather + concat -> x0 (1024 x 2048) ---------------
__global__ __launch_bounds__(256) void gather_kernel(const float* __restrict__ vis,
                                                     const float* __restrict__ inf,
                                                     const int* __restrict__ idx,
                                                     float* __restrict__ x0) {
    int r = blockIdx.x;            // 0 .. 1023
    int b = r >> 2, j = r & 3;
    int tok = (j < 3) ? (idx[b * 3 + j] + 1) : 0;   // gathered tokens are from [:,1:,:]; row 3 = CLS (token 0)
    const float4* v = (const float4*)(vis + (size_t)b * SS * CVD + (size_t)tok * CVD);
    const float4* w = (const float4*)(inf + (size_t)b * SS * CVD + (size_t)tok * CVD);
    float4* dst = (float4*)(x0 + (size_t)r * 2048);
    dst[threadIdx.x] = v[threadIdx.x];
    dst[256 + threadIdx.x] = w[threadIdx.x];
}

// ---------------- fp32 tiled GEMM: C[M,N] = A[M,K] @ W[K,N] + bias ------------
// 64x64 tile, 256 threads, 4x4 microtile, BK=16, next-tile register prefetch.
__global__ __launch_bounds__(256) void gemm_bias_kernel(const float* __restrict__ A,
                                                        const float* __restrict__ W,
                                                        const float* __restrict__ bias,
                                                        float* __restrict__ C,
                                                        int N, int K) {
    __shared__ float As[16][65];   // [k][m], padded
    __shared__ float Bs[16][64];   // [k][n]
    int t = threadIdx.x;
    int tx = t & 15, ty = t >> 4;
    int m0 = blockIdx.y * 64, n0 = blockIdx.x * 64;
    float acc[4][4] = {};

    int arow = t >> 2, acol = (t & 3) * 4;     // A tile: 64 rows x 16 k
    int brow = t >> 4, bcol = (t & 15) * 4;    // B tile: 16 k x 64 n
    const float* Ap = A + (size_t)(m0 + arow) * K + acol;
    const float* Wp = W + (size_t)brow * N + n0 + bcol;

    // prologue: load tile 0 into registers
    float4 av = *(const float4*)(Ap);
    float4 bv = *(const float4*)(Wp);

    for (int k0 = 0; k0 < K; k0 += 16) {
        // commit current tile to LDS
        As[acol + 0][arow] = av.x;
        As[acol + 1][arow] = av.y;
        As[acol + 2][arow] = av.z;
        As[acol + 3][arow] = av.w;
        *(float4*)&Bs[brow][bcol] = bv;
        __syncthreads();
        // issue NEXT tile's global loads now; latency hides under the FMA loop
        if (k0 + 16 < K) {
            av = *(const float4*)(Ap + k0 + 16);
            bv = *(const float4*)(Wp + (size_t)(k0 + 16) * N);
        }
#pragma unroll
        for (int k = 0; k < 16; ++k) {
            float4 a = *(const float4*)&As[k][ty * 4];
            float4 b = *(const float4*)&Bs[k][tx * 4];
            acc[0][0] += a.x * b.x; acc[0][1] += a.x * b.y; acc[0][2] += a.x * b.z; acc[0][3] += a.x * b.w;
            acc[1][0] += a.y * b.x; acc[1][1] += a.y * b.y; acc[1][2] += a.y * b.z; acc[1][3] += a.y * b.w;
            acc[2][0] += a.z * b.x; acc[2][1] += a.z * b.y; acc[2][2] += a.z * b.z; acc[2][3] += a.z * b.w;
            acc[3][0] += a.w * b.x; acc[3][1] += a.w * b.y; acc[3][2] += a.w * b.z; acc[3][3] += a.w * b.w;
        }
        __syncthreads();
    }
#pragma unroll
    for (int i = 0; i < 4; ++i) {
        int row = m0 + ty * 4 + i, col = n0 + tx * 4;
        float4 bvv = *(const float4*)(bias + col);
        float4 o;
        o.x = acc[i][0] + bvv.x;
        o.y = acc[i][1] + bvv.y;
        o.z = acc[i][2] + bvv.z;
        o.w = acc[i][3] + bvv.w;
        *(float4*)(C + (size_t)row * N + col) = o;
    }
}

// ---------------- LayerNorm (two-pass, register-resident) + leaky -------------
__device__ __forceinline__ float block_sum(float x, float* red) {
#pragma unroll
    for (int off = 32; off; off >>= 1) x += __shfl_xor(x, off);
    int wave = threadIdx.x >> 6, lane = threadIdx.x & 63;
    if (lane == 0) red[wave] = x;
    __syncthreads();
    float r = red[0] + red[1] + red[2] + red[3];
    __syncthreads();
    return r;
}

__global__ __launch_bounds__(256) void ln_leaky_kernel(const float* __restrict__ Y,
                                                       const float* __restrict__ g,
                                                       const float* __restrict__ be,
                                                       float* __restrict__ X) {
    __shared__ float red[4];
    int row = blockIdx.x;
    const float4* y = (const float4*)(Y + (size_t)row * CVD);
    float4 v = y[threadIdx.x];
    float s = v.x + v.y + v.z + v.w;
    float tot = block_sum(s, red);
    float mu = tot * (1.0f / CVD);
    float dx = v.x - mu, dy = v.y - mu, dz = v.z - mu, dw = v.w - mu;
    float sq = dx * dx + dy * dy + dz * dz + dw * dw;
    float tot2 = block_sum(sq, red);
    float var = tot2 * (1.0f / CVD);
    float rstd = rsqrtf(var + EPS_LN);
    float4 gg = ((const float4*)g)[threadIdx.x];
    float4 bb = ((const float4*)be)[threadIdx.x];
    float4 o;
    o.x = dx * rstd * gg.x + bb.x;
    o.y = dy * rstd * gg.y + bb.y;
    o.z = dz * rstd * gg.z + bb.z;
    o.w = dw * rstd * gg.w + bb.w;
    o.x = o.x >= 0.f ? o.x : NEG_SLOPE * o.x;
    o.y = o.y >= 0.f ? o.y : NEG_SLOPE * o.y;
    o.z = o.z >= 0.f ? o.z : NEG_SLOPE * o.z;
    o.w = o.w >= 0.f ? o.w : NEG_SLOPE * o.w;
    ((float4*)(X + (size_t)row * CVD))[threadIdx.x] = o;
}

extern "C" void kernel_launch(void* const* d_in, const int* in_sizes, int n_in,
                              void* d_out, int out_size, void* d_ws, size_t ws_size,
                              hipStream_t stream) {
    const float* vis = (const float*)d_in[0];
    const float* inf = (const float*)d_in[1];
    // d_in[2] = topk (always 3 for this problem shape)
    const float* W0 = (const float*)d_in[3];
    const float* b0 = (const float*)d_in[4];
    const float* g0 = (const float*)d_in[5];
    const float* be0 = (const float*)d_in[6];
    const float* W1 = (const float*)d_in[7];
    const float* b1 = (const float*)d_in[8];
    const float* g1 = (const float*)d_in[9];
    const float* be1 = (const float*)d_in[10];
    const float* W2 = (const float*)d_in[11];
    const float* b2 = (const float*)d_in[12];
    const float* g2 = (const float*)d_in[13];
    const float* be2 = (const float*)d_in[14];
    const float* W3 = (const float*)d_in[15];
    const float* b3 = (const float*)d_in[16];
    float* out = (float*)d_out;

    float* f = (float*)d_ws;
    float* cosv = f;                          // 65536 floats
    int* idx = (int*)(f + 65536);             // 768 ints
    float* x0 = f + 65536 + 1024;             // 1024 x 2048
    float* bufA = x0 + (size_t)MROWS * 2048;  // 1024 x 1024
    float* bufB = bufA + (size_t)MROWS * 1024;
    float* bufC = bufB + (size_t)MROWS * 1024;

    cos_kernel<<<dim3(16384), dim3(256), 0, stream>>>(vis, inf, cosv);
    topk_kernel<<<dim3(BB), dim3(64), 0, stream>>>(cosv, idx);
    gather_kernel<<<dim3(MROWS), dim3(256), 0, stream>>>(vis, inf, idx, x0);

    gemm_bias_kernel<<<dim3(16, 16), dim3(256), 0, stream>>>(x0, W0, b0, bufA, 1024, 2048);
    ln_leaky_kernel<<<dim3(MROWS), dim3(256), 0, stream>>>(bufA, g0, be0, bufB);

    gemm_bias_kernel<<<dim3(16, 16), dim3(256), 0, stream>>>(bufB, W1, b1, bufC, 1024, 1024);
    ln_leaky_kernel<<<dim3(MROWS), dim3(256), 0, stream>>>(bufC, g1, be1, bufA);

    gemm_bias_kernel<<<dim3(16, 16), dim3(256), 0, stream>>>(bufA, W2, b2, bufB, 1024, 1024);
    ln_leaky_kernel<<<dim3(MROWS), dim3(256), 0, stream>>>(bufB, g2, be2, bufC);

    gemm_bias_kernel<<<dim3(12, 16), dim3(256), 0, stream>>>(bufC, W3, b3, out, CTD, 1024);
}

// Round 3
// 652.048 us; speedup vs baseline: 1.2532x; 1.2532x over previous
//
#include <hip/hip_runtime.h>
#include <math.h>

#define BB 256
#define SS 257
#define CVD 1024
#define CTD 768
#define NTOK 256          // S-1
#define MROWS 1024        // B*4
#define EPS_LN 1e-5f
#define NEG_SLOPE 0.01f
#define LDKP 72           // LDS k-stride (64 + 8 pad) in bf16 elems -> 144B rows, 2-way banks (free)

typedef __bf16 bf16x8 __attribute__((ext_vector_type(8)));
typedef float f32x4 __attribute__((ext_vector_type(4)));
typedef unsigned short usx8 __attribute__((ext_vector_type(8)));
typedef unsigned short usx4 __attribute__((ext_vector_type(4)));

__device__ __forceinline__ unsigned short f2bf(float x) {
    unsigned u = __float_as_uint(x);
    unsigned r = u + 0x7FFFu + ((u >> 16) & 1u);   // round-to-nearest-even
    return (unsigned short)(r >> 16);
}
__device__ __forceinline__ float bf2f(unsigned short h) {
    return __uint_as_float(((unsigned)h) << 16);
}
__device__ __forceinline__ void cvt4(float a, float b, float c, float d, usx4& h, usx4& l) {
    h[0] = f2bf(a); l[0] = f2bf(a - bf2f(h[0]));
    h[1] = f2bf(b); l[1] = f2bf(b - bf2f(h[1]));
    h[2] = f2bf(c); l[2] = f2bf(c - bf2f(h[2]));
    h[3] = f2bf(d); l[3] = f2bf(d - bf2f(h[3]));
}

// ---------------- Phase A: cosine similarity, one wave per token-row ----------
__global__ __launch_bounds__(256) void cos_kernel(const float* __restrict__ vis,
                                                  const float* __restrict__ inf,
                                                  float* __restrict__ cosv) {
    int wave = threadIdx.x >> 6;
    int lane = threadIdx.x & 63;
    int r = blockIdx.x * 4 + wave;
    int b = r >> 8, s = r & 255;
    const float4* vrow = (const float4*)(vis + (size_t)b * SS * CVD + (size_t)(s + 1) * CVD);
    const float4* irow = (const float4*)(inf + (size_t)b * SS * CVD + (size_t)(s + 1) * CVD);
    float vv = 0.f, ii = 0.f, vi = 0.f;
#pragma unroll
    for (int j = 0; j < 4; ++j) {
        float4 v = vrow[j * 64 + lane];
        float4 w = irow[j * 64 + lane];
        vv += v.x * v.x + v.y * v.y + v.z * v.z + v.w * v.w;
        ii += w.x * w.x + w.y * w.y + w.z * w.z + w.w * w.w;
        vi += v.x * w.x + v.y * w.y + v.z * w.z + v.w * w.w;
    }
#pragma unroll
    for (int off = 32; off; off >>= 1) {
        vv += __shfl_xor(vv, off);
        ii += __shfl_xor(ii, off);
        vi += __shfl_xor(vi, off);
    }
    if (lane == 0) cosv[r] = vi / sqrtf(vv * ii);
}

// ---------------- Phase B1: top-3 per batch (ties -> lower index) -------------
__global__ __launch_bounds__(64) void topk_kernel(const float* __restrict__ cosv,
                                                  int* __restrict__ idx) {
    int b = blockIdx.x;
    int lane = threadIdx.x;
    float v[4];
    int id[4];
#pragma unroll
    for (int j = 0; j < 4; ++j) {
        id[j] = lane + j * 64;
        v[j] = cosv[b * NTOK + id[j]];
    }
    for (int round = 0; round < 3; ++round) {
        float bv = v[0];
        int bi = id[0];
#pragma unroll
        for (int j = 1; j < 4; ++j)
            if (v[j] > bv) { bv = v[j]; bi = id[j]; }
#pragma unroll
        for (int off = 32; off; off >>= 1) {
            float ov = __shfl_xor(bv, off);
            int oi = __shfl_xor(bi, off);
            if (ov > bv || (ov == bv && oi < bi)) { bv = ov; bi = oi; }
        }
        if (lane == 0) idx[b * 3 + round] = bi;
#pragma unroll
        for (int j = 0; j < 4; ++j)
            if (id[j] == bi) v[j] = -3.402823466e38f;
    }
}

// ---------------- Phase B2: gather + concat + fp32->bf16(hi,lo) ---------------
__global__ __launch_bounds__(256) void gather_conv_kernel(const float* __restrict__ vis,
                                                          const float* __restrict__ inf,
                                                          const int* __restrict__ idx,
                                                          unsigned short* __restrict__ x0h,
                                                          unsigned short* __restrict__ x0l) {
    int r = blockIdx.x, t = threadIdx.x;
    int b = r >> 2, j = r & 3;
    int tok = (j < 3) ? (idx[b * 3 + j] + 1) : 0;
    const float4* v = (const float4*)(vis + (size_t)b * SS * CVD + (size_t)tok * CVD);
    const float4* w = (const float4*)(inf + (size_t)b * SS * CVD + (size_t)tok * CVD);
    float4 a = v[t];
    float4 c = w[t];
    usx4 h, l;
    cvt4(a.x, a.y, a.z, a.w, h, l);
    *(usx4*)(x0h + (size_t)r * 2048 + t * 4) = h;
    *(usx4*)(x0l + (size_t)r * 2048 + t * 4) = l;
    cvt4(c.x, c.y, c.z, c.w, h, l);
    *(usx4*)(x0h + (size_t)r * 2048 + 1024 + t * 4) = h;
    *(usx4*)(x0l + (size_t)r * 2048 + 1024 + t * 4) = l;
}

// ---------------- Weight prep: fp32 W[K][N] -> bf16 hi/lo W^T[N][K] -----------
__global__ __launch_bounds__(256) void wprep_kernel(const float* __restrict__ W,
                                                    unsigned short* __restrict__ WTh,
                                                    unsigned short* __restrict__ WTl,
                                                    int K, int N) {
    __shared__ float tile[64][69];   // padded: column reads land 2-way (free)
    int k0 = blockIdx.x * 64, n0 = blockIdx.y * 64;
    int t = threadIdx.x;
    int r = t >> 4, c4 = (t & 15) * 4;
#pragma unroll
    for (int p = 0; p < 4; ++p) {
        float4 v = *(const float4*)(W + (size_t)(k0 + r + p * 16) * N + n0 + c4);
        tile[r + p * 16][c4 + 0] = v.x;
        tile[r + p * 16][c4 + 1] = v.y;
        tile[r + p * 16][c4 + 2] = v.z;
        tile[r + p * 16][c4 + 3] = v.w;
    }
    __syncthreads();
    int nn0 = t >> 4, kk = (t & 15) * 4;
#pragma unroll
    for (int p = 0; p < 4; ++p) {
        int nn = nn0 + p * 16;
        float a = tile[kk + 0][nn], b = tile[kk + 1][nn];
        float c = tile[kk + 2][nn], d = tile[kk + 3][nn];
        usx4 h, l;
        cvt4(a, b, c, d, h, l);
        *(usx4*)(WTh + (size_t)(n0 + nn) * K + k0 + kk) = h;
        *(usx4*)(WTl + (size_t)(n0 + nn) * K + k0 + kk) = l;
    }
}

// ---------------- split-bf16 MFMA GEMM: Cpart[z] = A[M,K-chunk] @ W^T ---------
// block 128x128, 4 waves of 64x64 (4x4 frags 16x16x32), BK=64, split-K via z.
__global__ __launch_bounds__(256, 1) void gemm_split_kernel(
        const unsigned short* __restrict__ Ah, const unsigned short* __restrict__ Al,
        const unsigned short* __restrict__ Bh, const unsigned short* __restrict__ Bl,
        float* __restrict__ Cpart, int N, int K, int KCH) {
    __shared__ unsigned short sAh[128 * LDKP], sAl[128 * LDKP];
    __shared__ unsigned short sBh[128 * LDKP], sBl[128 * LDKP];
    int t = threadIdx.x;
    int lane = t & 63, wid = t >> 6;
    int wm = (wid >> 1) * 64, wn = (wid & 1) * 64;
    int fr = lane & 15, kg = lane >> 4;
    int m0 = blockIdx.y * 128, n0 = blockIdx.x * 128;
    int kstart = blockIdx.z * KCH;
    int sm = t >> 1, skq = (t & 1) * 32;     // staging: row, k-quarter
    const usx8* gAh = (const usx8*)(Ah + (size_t)(m0 + sm) * K + kstart + skq);
    const usx8* gAl = (const usx8*)(Al + (size_t)(m0 + sm) * K + kstart + skq);
    const usx8* gBh = (const usx8*)(Bh + (size_t)(n0 + sm) * K + kstart + skq);
    const usx8* gBl = (const usx8*)(Bl + (size_t)(n0 + sm) * K + kstart + skq);

    f32x4 acc[4][4] = {};
    usx8 rah[4], ral[4], rbh[4], rbl[4];
    int nsteps = KCH >> 6;

#pragma unroll
    for (int s = 0; s < 4; ++s) { rah[s] = gAh[s]; ral[s] = gAl[s]; rbh[s] = gBh[s]; rbl[s] = gBl[s]; }

    for (int step = 0; step < nsteps; ++step) {
        int base = sm * LDKP + skq;
#pragma unroll
        for (int s = 0; s < 4; ++s) {
            *(usx8*)&sAh[base + s * 8] = rah[s];
            *(usx8*)&sAl[base + s * 8] = ral[s];
            *(usx8*)&sBh[base + s * 8] = rbh[s];
            *(usx8*)&sBl[base + s * 8] = rbl[s];
        }
        __syncthreads();
        if (step + 1 < nsteps) {                 // prefetch next step; latency hides under MFMAs
            int adv = (step + 1) * 8;            // 64 bf16 = 8 usx8
#pragma unroll
            for (int s = 0; s < 4; ++s) {
                rah[s] = gAh[adv + s]; ral[s] = gAl[adv + s];
                rbh[s] = gBh[adv + s]; rbl[s] = gBl[adv + s];
            }
        }
#pragma unroll
        for (int kc = 0; kc < 2; ++kc) {
            int kb = kc * 32 + kg * 8;
            bf16x8 ah[4], al[4];
#pragma unroll
            for (int i = 0; i < 4; ++i) {
                int ro = (wm + i * 16 + fr) * LDKP + kb;
                ah[i] = *(const bf16x8*)&sAh[ro];
                al[i] = *(const bf16x8*)&sAl[ro];
            }
#pragma unroll
            for (int j = 0; j < 4; ++j) {
                int co = (wn + j * 16 + fr) * LDKP + kb;
                bf16x8 bh = *(const bf16x8*)&sBh[co];
                bf16x8 bl = *(const bf16x8*)&sBl[co];
#pragma unroll
                for (int i = 0; i < 4; ++i) {
                    acc[i][j] = __builtin_amdgcn_mfma_f32_16x16x32_bf16(ah[i], bh, acc[i][j], 0, 0, 0);
                    acc[i][j] = __builtin_amdgcn_mfma_f32_16x16x32_bf16(ah[i], bl, acc[i][j], 0, 0, 0);
                    acc[i][j] = __builtin_amdgcn_mfma_f32_16x16x32_bf16(al[i], bh, acc[i][j], 0, 0, 0);
                }
            }
        }
        __syncthreads();
    }
    // epilogue: C/D layout col=lane&15, row=(lane>>4)*4+reg [m89-verified]
    float* Cp = Cpart + (size_t)blockIdx.z * MROWS * N;
#pragma unroll
    for (int i = 0; i < 4; ++i) {
#pragma unroll
        for (int j = 0; j < 4; ++j) {
            int row = m0 + wm + i * 16 + kg * 4;
            int col = n0 + wn + j * 16 + fr;
#pragma unroll
            for (int r = 0; r < 4; ++r)
                Cp[(size_t)(row + r) * N + col] = acc[i][j][r];
        }
    }
}

// ---------------- block reduce helper ----------------------------------------
__device__ __forceinline__ float block_sum(float x, float* red) {
#pragma unroll
    for (int off = 32; off; off >>= 1) x += __shfl_xor(x, off);
    int wave = threadIdx.x >> 6, lane = threadIdx.x & 63;
    if (lane == 0) red[wave] = x;
    __syncthreads();
    float r = red[0] + red[1] + red[2] + red[3];
    __syncthreads();
    return r;
}

// ---------------- split-K reduce + bias + LN + leaky + bf16(hi,lo) ------------
__global__ __launch_bounds__(256) void reduce_ln_kernel(const float* __restrict__ Cp,
                                                        const float* __restrict__ bias,
                                                        const float* __restrict__ g,
                                                        const float* __restrict__ be,
                                                        unsigned short* __restrict__ Xh,
                                                        unsigned short* __restrict__ Xl) {
    __shared__ float red[4];
    int row = blockIdx.x, t = threadIdx.x;
    float4 y0 = ((const float4*)(Cp + (size_t)row * CVD))[t];
    float4 y1 = ((const float4*)(Cp + 1048576 + (size_t)row * CVD))[t];
    float4 y2 = ((const float4*)(Cp + 2097152 + (size_t)row * CVD))[t];
    float4 y3 = ((const float4*)(Cp + 3145728 + (size_t)row * CVD))[t];
    float4 bv = ((const float4*)bias)[t];
    float vx = y0.x + y1.x + y2.x + y3.x + bv.x;
    float vy = y0.y + y1.y + y2.y + y3.y + bv.y;
    float vz = y0.z + y1.z + y2.z + y3.z + bv.z;
    float vw = y0.w + y1.w + y2.w + y3.w + bv.w;
    float tot = block_sum(vx + vy + vz + vw, red);
    float mu = tot * (1.0f / CVD);
    float dx = vx - mu, dy = vy - mu, dz = vz - mu, dw = vw - mu;
    float tot2 = block_sum(dx * dx + dy * dy + dz * dz + dw * dw, red);
    float rstd = rsqrtf(tot2 * (1.0f / CVD) + EPS_LN);
    float4 gg = ((const float4*)g)[t];
    float4 bb = ((const float4*)be)[t];
    float ox = dx * rstd * gg.x + bb.x;
    float oy = dy * rstd * gg.y + bb.y;
    float oz = dz * rstd * gg.z + bb.z;
    float ow = dw * rstd * gg.w + bb.w;
    ox = ox >= 0.f ? ox : NEG_SLOPE * ox;
    oy = oy >= 0.f ? oy : NEG_SLOPE * oy;
    oz = oz >= 0.f ? oz : NEG_SLOPE * oz;
    ow = ow >= 0.f ? ow : NEG_SLOPE * ow;
    usx4 h, l;
    cvt4(ox, oy, oz, ow, h, l);
    *(usx4*)(Xh + (size_t)row * CVD + t * 4) = h;
    *(usx4*)(Xl + (size_t)row * CVD + t * 4) = l;
}

// ---------------- final: split-K reduce + bias -> fp32 out --------------------
__global__ __launch_bounds__(192) void reduce_out_kernel(const float* __restrict__ Cp,
                                                         const float* __restrict__ bias,
                                                         float* __restrict__ out) {
    int row = blockIdx.x, t = threadIdx.x;
    float4 y0 = ((const float4*)(Cp + (size_t)row * CTD))[t];
    float4 y1 = ((const float4*)(Cp + 786432 + (size_t)row * CTD))[t];
    float4 y2 = ((const float4*)(Cp + 1572864 + (size_t)row * CTD))[t];
    float4 y3 = ((const float4*)(Cp + 2359296 + (size_t)row * CTD))[t];
    float4 bv = ((const float4*)bias)[t];
    float4 o;
    o.x = y0.x + y1.x + y2.x + y3.x + bv.x;
    o.y = y0.y + y1.y + y2.y + y3.y + bv.y;
    o.z = y0.z + y1.z + y2.z + y3.z + bv.z;
    o.w = y0.w + y1.w + y2.w + y3.w + bv.w;
    ((float4*)(out + (size_t)row * CTD))[t] = o;
}

extern "C" void kernel_launch(void* const* d_in, const int* in_sizes, int n_in,
                              void* d_out, int out_size, void* d_ws, size_t ws_size,
                              hipStream_t stream) {
    const float* vis = (const float*)d_in[0];
    const float* inf = (const float*)d_in[1];
    const float* W0 = (const float*)d_in[3];
    const float* b0 = (const float*)d_in[4];
    const float* g0 = (const float*)d_in[5];
    const float* be0 = (const float*)d_in[6];
    const float* W1 = (const float*)d_in[7];
    const float* b1 = (const float*)d_in[8];
    const float* g1 = (const float*)d_in[9];
    const float* be1 = (const float*)d_in[10];
    const float* W2 = (const float*)d_in[11];
    const float* b2 = (const float*)d_in[12];
    const float* g2 = (const float*)d_in[13];
    const float* be2 = (const float*)d_in[14];
    const float* W3 = (const float*)d_in[15];
    const float* b3 = (const float*)d_in[16];
    float* out = (float*)d_out;

    char* ws = (char*)d_ws;
    float* cosv = (float*)(ws + 0x0);                      // 256 KB
    int* idx = (int*)(ws + 0x40000);                       // 4 KB
    unsigned short* x0h = (unsigned short*)(ws + 0x50000);  // 4 MB
    unsigned short* x0l = (unsigned short*)(ws + 0x450000); // 4 MB
    unsigned short* Xh = (unsigned short*)(ws + 0x850000);  // 2 MB
    unsigned short* Xl = (unsigned short*)(ws + 0xA50000);  // 2 MB
    unsigned short* W0h = (unsigned short*)(ws + 0xC50000); // 4 MB
    unsigned short* W0l = (unsigned short*)(ws + 0x1050000);
    unsigned short* W1h = (unsigned short*)(ws + 0x1450000);// 2 MB
    unsigned short* W1l = (unsigned short*)(ws + 0x1650000);
    unsigned short* W2h = (unsigned short*)(ws + 0x1850000);
    unsigned short* W2l = (unsigned short*)(ws + 0x1A50000);
    unsigned short* W3h = (unsigned short*)(ws + 0x1C50000);// 1.5 MB
    unsigned short* W3l = (unsigned short*)(ws + 0x1DD0000);
    float* Cpart = (float*)(ws + 0x1F50000);               // 16 MB

    cos_kernel<<<dim3(16384), dim3(256), 0, stream>>>(vis, inf, cosv);
    topk_kernel<<<dim3(BB), dim3(64), 0, stream>>>(cosv, idx);
    gather_conv_kernel<<<dim3(MROWS), dim3(256), 0, stream>>>(vis, inf, idx, x0h, x0l);

    wprep_kernel<<<dim3(32, 16), dim3(256), 0, stream>>>(W0, W0h, W0l, 2048, 1024);
    wprep_kernel<<<dim3(16, 16), dim3(256), 0, stream>>>(W1, W1h, W1l, 1024, 1024);
    wprep_kernel<<<dim3(16, 16), dim3(256), 0, stream>>>(W2, W2h, W2l, 1024, 1024);
    wprep_kernel<<<dim3(16, 12), dim3(256), 0, stream>>>(W3, W3h, W3l, 1024, 768);

    gemm_split_kernel<<<dim3(8, 8, 4), dim3(256), 0, stream>>>(x0h, x0l, W0h, W0l, Cpart, 1024, 2048, 512);
    reduce_ln_kernel<<<dim3(MROWS), dim3(256), 0, stream>>>(Cpart, b0, g0, be0, Xh, Xl);

    gemm_split_kernel<<<dim3(8, 8, 4), dim3(256), 0, stream>>>(Xh, Xl, W1h, W1l, Cpart, 1024, 1024, 256);
    reduce_ln_kernel<<<dim3(MROWS), dim3(256), 0, stream>>>(Cpart, b1, g1, be1, Xh, Xl);

    gemm_split_kernel<<<dim3(8, 8, 4), dim3(256), 0, stream>>>(Xh, Xl, W2h, W2l, Cpart, 1024, 1024, 256);
    reduce_ln_kernel<<<dim3(MROWS), dim3(256), 0, stream>>>(Cpart, b2, g2, be2, Xh, Xl);

    gemm_split_kernel<<<dim3(6, 8, 4), dim3(256), 0, stream>>>(Xh, Xl, W3h, W3l, Cpart, 768, 1024, 256);
    reduce_out_kernel<<<dim3(MROWS), dim3(192), 0, stream>>>(Cpart, b3, out);
}